// Round 1
// baseline (701.905 us; speedup 1.0000x reference)
//
#include <hip/hip_runtime.h>

// Grid_INR2D: fused bilinear grid-sample (4 pyramid levels, 16ch each) +
// per-pixel MLP 96 -> 64 -> relu -> 64 -> relu -> 3.
// B=8, H=W=256. All fp32.
//
// Design notes (round 1, fp32 correctness baseline):
//  - 1 thread = 1 pixel, 2 batches per thread (gridDim.y = 4 batch-slices).
//    The 64 sampled "local" channels are batch-independent -> computed once
//    per thread, reused across its 2 batches.
//  - Weights are read with wave-uniform addresses from fully-unrolled loops
//    -> compiler emits s_load into SGPRs; FMAs take the SGPR operand
//    directly (no LDS, no per-FMA ds_read cost).
//  - All register arrays indexed by compile-time-unrolled indices only.

#define HWPIX 65536

__global__ __launch_bounds__(256, 2) void grid_inr_kernel(
    const float* __restrict__ feat,
    const float* __restrict__ g0, const float* __restrict__ g1,
    const float* __restrict__ g2, const float* __restrict__ g3,
    const float* __restrict__ w1, const float* __restrict__ b1,
    const float* __restrict__ w2, const float* __restrict__ b2,
    const float* __restrict__ w3, const float* __restrict__ b3,
    float* __restrict__ out)
{
    const int p  = blockIdx.x * blockDim.x + threadIdx.x;  // pixel id
    const int px = p & 255;
    const int py = p >> 8;

    // ---- bilinear sample 4 grids x 16 channels -> local[64] (batch-indep)
    float local[64];
    const float* gs[4] = {g0, g1, g2, g3};
    const int    gn[4] = {32, 64, 128, 256};

#pragma unroll
    for (int l = 0; l < 4; ++l) {
        const int G = gn[l];
        // xs = -1 + 1/256 + 2*px/256 ; ix = (xs+1)*0.5*(G-1) = (2px+1)(G-1)/512
        // exact in fp32 (integer numerator < 2^17).
        const float ix = (float)((2 * px + 1) * (G - 1)) * (1.0f / 512.0f);
        const float iy = (float)((2 * py + 1) * (G - 1)) * (1.0f / 512.0f);
        int ix0 = (int)ix;            // ix >= 0, trunc == floor
        int iy0 = (int)iy;
        if (ix0 > G - 1) ix0 = G - 1;
        if (iy0 > G - 1) iy0 = G - 1;
        const int ix1 = (ix0 + 1 < G - 1) ? (ix0 + 1) : (G - 1);
        const int iy1 = (iy0 + 1 < G - 1) ? (iy0 + 1) : (G - 1);
        const float wx = ix - (float)ix0;
        const float wy = iy - (float)iy0;
        const float w00 = (1.0f - wy) * (1.0f - wx);
        const float w01 = (1.0f - wy) * wx;
        const float w10 = wy * (1.0f - wx);
        const float w11 = wy * wx;
        const int o00 = iy0 * G + ix0;
        const int o01 = iy0 * G + ix1;
        const int o10 = iy1 * G + ix0;
        const int o11 = iy1 * G + ix1;
        const float* g = gs[l];
        const int GG = G * G;
#pragma unroll
        for (int c = 0; c < 16; ++c) {
            const float* gc = g + c * GG;
            local[l * 16 + c] = gc[o00] * w00 + gc[o01] * w01 +
                                gc[o10] * w10 + gc[o11] * w11;
        }
    }

    // ---- per-batch MLP (2 batches per thread)
#pragma unroll 1
    for (int bi = 0; bi < 2; ++bi) {
        const int b = blockIdx.y * 2 + bi;

        float fx[32];
#pragma unroll
        for (int c = 0; c < 32; ++c)
            fx[c] = feat[(((b << 5) + c) << 16) + p];   // coalesced per channel

        // layer 1: 96 -> 64, relu. Weight addresses wave-uniform -> s_load.
        float h1[64];
#pragma unroll
        for (int j = 0; j < 64; ++j) {
            float acc = b1[j];
            const float* wj = w1 + j * 96;
#pragma unroll
            for (int k = 0; k < 32; ++k) acc = fmaf(fx[k],    wj[k],      acc);
#pragma unroll
            for (int k = 0; k < 64; ++k) acc = fmaf(local[k], wj[32 + k], acc);
            h1[j] = fmaxf(acc, 0.0f);
        }

        // layer 2: 64 -> 64, relu
        float h2[64];
#pragma unroll
        for (int j = 0; j < 64; ++j) {
            float acc = b2[j];
            const float* wj = w2 + j * 64;
#pragma unroll
            for (int k = 0; k < 64; ++k) acc = fmaf(h1[k], wj[k], acc);
            h2[j] = fmaxf(acc, 0.0f);
        }

        // layer 3: 64 -> 3, write out[(b*3+o)*65536 + p]
#pragma unroll
        for (int o = 0; o < 3; ++o) {
            float acc = b3[o];
            const float* wj = w3 + o * 64;
#pragma unroll
            for (int k = 0; k < 64; ++k) acc = fmaf(h2[k], wj[k], acc);
            out[(((b * 3) + o) << 16) + p] = acc;
        }
    }
}

extern "C" void kernel_launch(void* const* d_in, const int* in_sizes, int n_in,
                              void* d_out, int out_size, void* d_ws, size_t ws_size,
                              hipStream_t stream) {
    const float* feat = (const float*)d_in[0];
    const float* g0   = (const float*)d_in[1];
    const float* g1   = (const float*)d_in[2];
    const float* g2   = (const float*)d_in[3];
    const float* g3   = (const float*)d_in[4];
    const float* w1   = (const float*)d_in[5];
    const float* b1   = (const float*)d_in[6];
    const float* w2   = (const float*)d_in[7];
    const float* b2   = (const float*)d_in[8];
    const float* w3   = (const float*)d_in[9];
    const float* b3   = (const float*)d_in[10];

    dim3 grid(HWPIX / 256, 4);  // 256 pixel-blocks x 4 batch-slices (2 b each)
    grid_inr_kernel<<<grid, 256, 0, stream>>>(
        feat, g0, g1, g2, g3, w1, b1, w2, b2, w3, b3, (float*)d_out);
}

// Round 2
// 503.877 us; speedup vs baseline: 1.3930x; 1.3930x over previous
//
#include <hip/hip_runtime.h>

// Grid_INR2D: fused bilinear grid-sample (4 pyramid levels, 16ch each) +
// per-pixel MLP 96 -> 64 -> relu -> 64 -> relu -> 3.  B=8, H=W=256, fp32.
//
// Round 2: kill register spilling (round 1: 128 VGPR + ~190MB scratch write).
//  - hl[j] = b1[j] + dot(local, w1[j,32:96]) precomputed once per pixel
//    (batch-independent 2/3 of layer 1); local[] dies afterwards.
//  - layer 3 fused into layer 2: h2[j] consumed immediately, no h2[] array.
//  - 4 batches per thread (gridDim.y=2), batch loop NOT unrolled to keep
//    code ~90KB; all register arrays indexed by fully-unrolled indices only.
//  - __launch_bounds__(256, 1): allow ~200 VGPR, 2 waves/SIMD, zero spill.

#define HWPIX 65536

__global__ __launch_bounds__(256, 1) void grid_inr_kernel(
    const float* __restrict__ feat,
    const float* __restrict__ g0, const float* __restrict__ g1,
    const float* __restrict__ g2, const float* __restrict__ g3,
    const float* __restrict__ w1, const float* __restrict__ b1,
    const float* __restrict__ w2, const float* __restrict__ b2,
    const float* __restrict__ w3, const float* __restrict__ b3,
    float* __restrict__ out)
{
    const int p  = blockIdx.x * blockDim.x + threadIdx.x;  // pixel id
    const int px = p & 255;
    const int py = p >> 8;

    // ---- bilinear sample 4 grids x 16 channels -> local[64] (batch-indep)
    float local[64];
    {
        const float* gs[4] = {g0, g1, g2, g3};
        const int    gn[4] = {32, 64, 128, 256};
#pragma unroll
        for (int l = 0; l < 4; ++l) {
            const int G = gn[l];
            // ix = (xs+1)*0.5*(G-1) = (2px+1)(G-1)/512, exact in fp32.
            const float ix = (float)((2 * px + 1) * (G - 1)) * (1.0f / 512.0f);
            const float iy = (float)((2 * py + 1) * (G - 1)) * (1.0f / 512.0f);
            int ix0 = (int)ix;
            int iy0 = (int)iy;
            if (ix0 > G - 1) ix0 = G - 1;
            if (iy0 > G - 1) iy0 = G - 1;
            const int ix1 = (ix0 + 1 < G - 1) ? (ix0 + 1) : (G - 1);
            const int iy1 = (iy0 + 1 < G - 1) ? (iy0 + 1) : (G - 1);
            const float wx = ix - (float)ix0;
            const float wy = iy - (float)iy0;
            const float w00 = (1.0f - wy) * (1.0f - wx);
            const float w01 = (1.0f - wy) * wx;
            const float w10 = wy * (1.0f - wx);
            const float w11 = wy * wx;
            const int o00 = iy0 * G + ix0;
            const int o01 = iy0 * G + ix1;
            const int o10 = iy1 * G + ix0;
            const int o11 = iy1 * G + ix1;
            const float* g = gs[l];
            const int GG = G * G;
#pragma unroll
            for (int c = 0; c < 16; ++c) {
                const float* gc = g + c * GG;
                local[l * 16 + c] = gc[o00] * w00 + gc[o01] * w01 +
                                    gc[o10] * w10 + gc[o11] * w11;
            }
        }
    }

    // ---- hl[j] = b1[j] + dot(local, w1[j, 32:96])   (batch-independent)
    float hl[64];
#pragma unroll
    for (int j = 0; j < 64; ++j) {
        const float* wj = w1 + j * 96 + 32;
        float a0 = b1[j], a1 = 0.f, a2 = 0.f, a3 = 0.f;
#pragma unroll
        for (int k = 0; k < 64; k += 4) {
            a0 = fmaf(local[k],     wj[k],     a0);
            a1 = fmaf(local[k + 1], wj[k + 1], a1);
            a2 = fmaf(local[k + 2], wj[k + 2], a2);
            a3 = fmaf(local[k + 3], wj[k + 3], a3);
        }
        hl[j] = (a0 + a1) + (a2 + a3);
    }
    // local[] dead from here on.

    // ---- per-batch MLP (4 batches per thread, loop body shared)
#pragma unroll 1
    for (int bi = 0; bi < 4; ++bi) {
        const int b = (blockIdx.y << 2) + bi;

        float fx[32];
#pragma unroll
        for (int c = 0; c < 32; ++c)
            fx[c] = feat[(((b << 5) + c) << 16) + p];   // coalesced

        // layer 1 (batch-dependent third): h1[j] = relu(hl[j] + fx . w1[j,0:32])
        float h1[64];
#pragma unroll
        for (int j = 0; j < 64; ++j) {
            const float* wj = w1 + j * 96;
            float a0 = hl[j], a1 = 0.f, a2 = 0.f, a3 = 0.f;
#pragma unroll
            for (int k = 0; k < 32; k += 4) {
                a0 = fmaf(fx[k],     wj[k],     a0);
                a1 = fmaf(fx[k + 1], wj[k + 1], a1);
                a2 = fmaf(fx[k + 2], wj[k + 2], a2);
                a3 = fmaf(fx[k + 3], wj[k + 3], a3);
            }
            h1[j] = fmaxf((a0 + a1) + (a2 + a3), 0.0f);
        }

        // layer 2 + fused layer 3: h2[j] consumed immediately.
        float o0 = b3[0], o1 = b3[1], o2 = b3[2];
#pragma unroll
        for (int j = 0; j < 64; ++j) {
            const float* wj = w2 + j * 64;
            float a0 = b2[j], a1 = 0.f, a2 = 0.f, a3 = 0.f;
#pragma unroll
            for (int k = 0; k < 64; k += 4) {
                a0 = fmaf(h1[k],     wj[k],     a0);
                a1 = fmaf(h1[k + 1], wj[k + 1], a1);
                a2 = fmaf(h1[k + 2], wj[k + 2], a2);
                a3 = fmaf(h1[k + 3], wj[k + 3], a3);
            }
            const float h2j = fmaxf((a0 + a1) + (a2 + a3), 0.0f);
            o0 = fmaf(h2j, w3[j],        o0);
            o1 = fmaf(h2j, w3[64 + j],   o1);
            o2 = fmaf(h2j, w3[128 + j],  o2);
        }

        out[((b * 3 + 0) << 16) + p] = o0;
        out[((b * 3 + 1) << 16) + p] = o1;
        out[((b * 3 + 2) << 16) + p] = o2;
    }
}

extern "C" void kernel_launch(void* const* d_in, const int* in_sizes, int n_in,
                              void* d_out, int out_size, void* d_ws, size_t ws_size,
                              hipStream_t stream) {
    const float* feat = (const float*)d_in[0];
    const float* g0   = (const float*)d_in[1];
    const float* g1   = (const float*)d_in[2];
    const float* g2   = (const float*)d_in[3];
    const float* g3   = (const float*)d_in[4];
    const float* w1   = (const float*)d_in[5];
    const float* b1   = (const float*)d_in[6];
    const float* w2   = (const float*)d_in[7];
    const float* b2   = (const float*)d_in[8];
    const float* w3   = (const float*)d_in[9];
    const float* b3   = (const float*)d_in[10];

    dim3 grid(HWPIX / 256, 2);  // 256 pixel-blocks x 2 batch-slices (4 b each)
    grid_inr_kernel<<<grid, 256, 0, stream>>>(
        feat, g0, g1, g2, g3, w1, b1, w2, b2, w3, b3, (float*)d_out);
}

// Round 3
// 42.673 us; speedup vs baseline: 16.4484x; 11.8078x over previous
//
#include <hip/hip_runtime.h>

// Grid_INR2D round 3: bf16-MFMA reformulation.
// MLP as 3 chained GEMMs, M=out-ch, N=pixels, K=in-ch, using
// v_mfma_f32_16x16x32_bf16. Fragment-layout identity used throughout:
//   A-frag : row = lane&15, k = 4*(lane>>4) + (e&3) + 16*(e>>2)
//   B-frag : col = lane&15, k = same formula
//   C/D    : col = lane&15, row = 4*(lane>>4) + reg     (m89-verified)
// => C-frag of layer n IS the B-frag of layer n+1 per-lane:
//   Bfrag[kb].e = bf16(relu(Cfrag[mt=2*kb + (e>=4)].reg[e&3]))  -- no LDS.
//
// Org: wave = 32 pixels (2 N-tiles) x all 8 batches (grid-sample once,
// straight into bf16 B-frags). Weights live in per-lane A-frags (~140 VGPR
// persistent). 512 blocks x 256 thr; no LDS; launch_bounds(256,1).

typedef float f32x4 __attribute__((ext_vector_type(4)));
typedef short s16x8 __attribute__((ext_vector_type(8)));

#define MFMA16(a, b, c) __builtin_amdgcn_mfma_f32_16x16x32_bf16((a), (b), (c), 0, 0, 0)

__device__ __forceinline__ short f2bf(float f) {  // fp32 -> bf16, RNE
    unsigned u = __builtin_bit_cast(unsigned, f);
    u += 0x7fff + ((u >> 16) & 1);
    return (short)(u >> 16);
}

__device__ __forceinline__ s16x8 pack_relu(const f32x4 lo, const f32x4 hi) {
    s16x8 r;
#pragma unroll
    for (int e = 0; e < 4; ++e) {
        r[e]     = f2bf(fmaxf(lo[e], 0.0f));
        r[e + 4] = f2bf(fmaxf(hi[e], 0.0f));
    }
    return r;
}

__global__ __launch_bounds__(256, 1) void grid_inr_mfma(
    const float* __restrict__ feat,
    const float* __restrict__ g0, const float* __restrict__ g1,
    const float* __restrict__ g2, const float* __restrict__ g3,
    const float* __restrict__ w1, const float* __restrict__ b1,
    const float* __restrict__ w2, const float* __restrict__ b2,
    const float* __restrict__ w3, const float* __restrict__ b3,
    float* __restrict__ out)
{
    const int lane  = threadIdx.x & 63;
    const int col   = lane & 15;    // N-index within 16-tile / A row / B col
    const int lrow  = lane >> 4;    // 0..3 : k-group
    const int wv    = threadIdx.x >> 6;
    const int pbase = blockIdx.x * 128 + wv * 32;   // 32 pixels per wave

    // ---------------- one-time: weight A-frags + bias frags ----------------
    s16x8 w1f[4][3], w2f[4][2], w3f[2];
    f32x4 b1f[4], b2f[4], b3f;
#pragma unroll
    for (int mt = 0; mt < 4; ++mt) {
#pragma unroll
        for (int kb = 0; kb < 3; ++kb) {
            const float* wr = w1 + (16 * mt + col) * 96 + 32 * kb + 4 * lrow;
#pragma unroll
            for (int e = 0; e < 8; ++e)
                w1f[mt][kb][e] = f2bf(wr[(e & 3) + 16 * (e >> 2)]);
        }
#pragma unroll
        for (int kb = 0; kb < 2; ++kb) {
            const float* wr = w2 + (16 * mt + col) * 64 + 32 * kb + 4 * lrow;
#pragma unroll
            for (int e = 0; e < 8; ++e)
                w2f[mt][kb][e] = f2bf(wr[(e & 3) + 16 * (e >> 2)]);
        }
#pragma unroll
        for (int r = 0; r < 4; ++r) {
            b1f[mt][r] = b1[16 * mt + 4 * lrow + r];
            b2f[mt][r] = b2[16 * mt + 4 * lrow + r];
        }
    }
    {
        const int row3 = (col < 3) ? col : 2;   // clamp, rows 3..15 unused
#pragma unroll
        for (int kb = 0; kb < 2; ++kb) {
            const float* wr = w3 + row3 * 64 + 32 * kb + 4 * lrow;
#pragma unroll
            for (int e = 0; e < 8; ++e)
                w3f[kb][e] = f2bf(wr[(e & 3) + 16 * (e >> 2)]);
        }
#pragma unroll
        for (int r = 0; r < 4; ++r) {
            const int ch = 4 * lrow + r;
            b3f[r] = b3[(ch < 3) ? ch : 0];     // junk rows never stored
        }
    }

    // ---------------- one-time: grid-sample -> local B-frags ----------------
    // localB[kb][nt]: local channels 32*kb + k(lane,e), pixel 16*nt + col.
    s16x8 localB[2][2];
    {
        const float* gs[4] = {g0, g1, g2, g3};
        const int    gn[4] = {32, 64, 128, 256};
#pragma unroll
        for (int nt = 0; nt < 2; ++nt) {
            const int p  = pbase + nt * 16 + col;
            const int px = p & 255;
            const int py = p >> 8;
#pragma unroll
            for (int lv = 0; lv < 4; ++lv) {
                const int G = gn[lv];
                // ix = (2px+1)(G-1)/512, exact in fp32 (verified rounds 1-2)
                const float ix = (float)((2 * px + 1) * (G - 1)) * (1.0f / 512.0f);
                const float iy = (float)((2 * py + 1) * (G - 1)) * (1.0f / 512.0f);
                int ix0 = (int)ix;
                int iy0 = (int)iy;
                if (ix0 > G - 1) ix0 = G - 1;
                if (iy0 > G - 1) iy0 = G - 1;
                const int ix1 = (ix0 + 1 < G - 1) ? (ix0 + 1) : (G - 1);
                const int iy1 = (iy0 + 1 < G - 1) ? (iy0 + 1) : (G - 1);
                const float wx = ix - (float)ix0;
                const float wy = iy - (float)iy0;
                const float w00 = (1.0f - wy) * (1.0f - wx);
                const float w01 = (1.0f - wy) * wx;
                const float w10 = wy * (1.0f - wx);
                const float w11 = wy * wx;
                const int o00 = iy0 * G + ix0;
                const int o01 = iy0 * G + ix1;
                const int o10 = iy1 * G + ix0;
                const int o11 = iy1 * G + ix1;
                const float* g = gs[lv];
                const int GG = G * G;
#pragma unroll
                for (int j = 0; j < 4; ++j) {
                    const float* gc = g + (4 * lrow + j) * GG;  // ch within level
                    const float v = gc[o00] * w00 + gc[o01] * w01 +
                                    gc[o10] * w10 + gc[o11] * w11;
                    localB[lv >> 1][nt][(lv & 1) * 4 + j] = f2bf(v);
                }
            }
        }
    }

    // ---------------- per-batch: feat load + 3 chained GEMMs ----------------
#pragma unroll 1
    for (int b = 0; b < 8; ++b) {
        // issue feat loads early (raw f32); consumed after local-grid MFMAs
        float raw[2][8];
#pragma unroll
        for (int nt = 0; nt < 2; ++nt) {
            const int p = pbase + nt * 16 + col;
#pragma unroll
            for (int e = 0; e < 8; ++e) {
                const int fc = 4 * lrow + (e & 3) + 16 * (e >> 2);
                raw[nt][e] = feat[(((b << 5) + fc) << 16) + p];
            }
        }

        // layer 1: C1[ch 0..63][px], K = 96 (kb0 = feat, kb1/2 = local)
        f32x4 c1[2][4];
#pragma unroll
        for (int nt = 0; nt < 2; ++nt)
#pragma unroll
            for (int mt = 0; mt < 4; ++mt) c1[nt][mt] = b1f[mt];
#pragma unroll
        for (int nt = 0; nt < 2; ++nt)
#pragma unroll
            for (int mt = 0; mt < 4; ++mt) {
                c1[nt][mt] = MFMA16(w1f[mt][1], localB[0][nt], c1[nt][mt]);
                c1[nt][mt] = MFMA16(w1f[mt][2], localB[1][nt], c1[nt][mt]);
            }
        s16x8 ff[2];
#pragma unroll
        for (int nt = 0; nt < 2; ++nt)
#pragma unroll
            for (int e = 0; e < 8; ++e) ff[nt][e] = f2bf(raw[nt][e]);
#pragma unroll
        for (int nt = 0; nt < 2; ++nt)
#pragma unroll
            for (int mt = 0; mt < 4; ++mt)
                c1[nt][mt] = MFMA16(w1f[mt][0], ff[nt], c1[nt][mt]);

        // relu + repack: C1-frag IS next layer's B-frag per-lane
        s16x8 h1b[2][2];
#pragma unroll
        for (int nt = 0; nt < 2; ++nt)
#pragma unroll
            for (int kb = 0; kb < 2; ++kb)
                h1b[nt][kb] = pack_relu(c1[nt][2 * kb], c1[nt][2 * kb + 1]);

        // layer 2
        f32x4 c2[2][4];
#pragma unroll
        for (int nt = 0; nt < 2; ++nt)
#pragma unroll
            for (int mt = 0; mt < 4; ++mt) c2[nt][mt] = b2f[mt];
#pragma unroll
        for (int nt = 0; nt < 2; ++nt)
#pragma unroll
            for (int mt = 0; mt < 4; ++mt) {
                c2[nt][mt] = MFMA16(w2f[mt][0], h1b[nt][0], c2[nt][mt]);
                c2[nt][mt] = MFMA16(w2f[mt][1], h1b[nt][1], c2[nt][mt]);
            }

        s16x8 h2b[2][2];
#pragma unroll
        for (int nt = 0; nt < 2; ++nt)
#pragma unroll
            for (int kb = 0; kb < 2; ++kb)
                h2b[nt][kb] = pack_relu(c2[nt][2 * kb], c2[nt][2 * kb + 1]);

        // layer 3: M=16 tile, rows 0..2 valid
        f32x4 c3[2];
#pragma unroll
        for (int nt = 0; nt < 2; ++nt) {
            c3[nt] = b3f;
            c3[nt] = MFMA16(w3f[0], h2b[nt][0], c3[nt]);
            c3[nt] = MFMA16(w3f[1], h2b[nt][1], c3[nt]);
        }

        // store: lanes 0..15 hold rows 0..3 (reg = row); write ch 0..2
        if (lrow == 0) {
#pragma unroll
            for (int nt = 0; nt < 2; ++nt) {
                const int p = pbase + nt * 16 + col;
                out[((b * 3 + 0) << 16) + p] = c3[nt][0];
                out[((b * 3 + 1) << 16) + p] = c3[nt][1];
                out[((b * 3 + 2) << 16) + p] = c3[nt][2];
            }
        }
    }
}

extern "C" void kernel_launch(void* const* d_in, const int* in_sizes, int n_in,
                              void* d_out, int out_size, void* d_ws, size_t ws_size,
                              hipStream_t stream) {
    const float* feat = (const float*)d_in[0];
    const float* g0   = (const float*)d_in[1];
    const float* g1   = (const float*)d_in[2];
    const float* g2   = (const float*)d_in[3];
    const float* g3   = (const float*)d_in[4];
    const float* w1   = (const float*)d_in[5];
    const float* b1   = (const float*)d_in[6];
    const float* w2   = (const float*)d_in[7];
    const float* b2   = (const float*)d_in[8];
    const float* w3   = (const float*)d_in[9];
    const float* b3   = (const float*)d_in[10];

    // 65536 pixels / (32 px/wave * 4 waves) = 512 blocks; batches inside.
    grid_inr_mfma<<<512, 256, 0, stream>>>(
        feat, g0, g1, g2, g3, w1, b1, w2, b2, w3, b3, (float*)d_out);
}

// Round 4
// 33.335 us; speedup vs baseline: 21.0563x; 1.2801x over previous
//
#include <hip/hip_runtime.h>

// Grid_INR2D round 4: bf16-MFMA chain + weights-in-LDS + pipelined feat.
//  - Round 3 was latency-bound: 140 persistent VGPRs of weight frags ->
//    164 VGPR -> 2 waves/SIMD; replays with feat fully L3-cached still 51us.
//  - Fix: stage the 22 per-lane A-frags (s16x8, pre-swizzled) in LDS once
//    per block (22.5KB); ds_read_b128 per MFMA (lane-contiguous 16B -> 2-way
//    bank aliasing = free). Persistent VGPR ~50 -> target <=128 with
//    __launch_bounds__(256,2) -> 4 waves/SIMD.
//  - 16 px/wave, 8 batches/thread -> 1024 blocks = 4 blocks/CU.
//  - feat software-pipelined: batch b+1's 8 loads issued after b's convert,
//    hidden under layer2/3 + next local MFMAs. Single raw[] buffer.
// Fragment identity (m89-verified, validated in round 3):
//   A: row=lane&15, k=4*(lane>>4)+(e&3)+16*(e>>2); B: col=lane&15, same k;
//   C/D: col=lane&15, row=4*(lane>>4)+reg  ==> C-frag of layer n is B-frag
//   of layer n+1 per-lane: B[kb].e = bf16(relu(C[2kb+(e>=4)].reg[e&3])).

typedef float f32x4 __attribute__((ext_vector_type(4)));
typedef short s16x8 __attribute__((ext_vector_type(8)));

#define MFMA16(a, b, c) __builtin_amdgcn_mfma_f32_16x16x32_bf16((a), (b), (c), 0, 0, 0)

__device__ __forceinline__ short f2bf(float f) {  // fp32 -> bf16, RNE
    unsigned u = __builtin_bit_cast(unsigned, f);
    u += 0x7fff + ((u >> 16) & 1);
    return (short)(u >> 16);
}

__device__ __forceinline__ s16x8 pack_relu(const f32x4 lo, const f32x4 hi) {
    s16x8 r;
#pragma unroll
    for (int e = 0; e < 4; ++e) {
        r[e]     = f2bf(fmaxf(lo[e], 0.0f));
        r[e + 4] = f2bf(fmaxf(hi[e], 0.0f));
    }
    return r;
}

// LDS frag table: fid 0..11 = w1[mt*3+kb], 12..19 = w2[mt*2+kb], 20..21 = w3[kb]
#define NFRAG 22

__global__ __launch_bounds__(256, 2) void grid_inr_mfma(
    const float* __restrict__ feat,
    const float* __restrict__ g0, const float* __restrict__ g1,
    const float* __restrict__ g2, const float* __restrict__ g3,
    const float* __restrict__ w1, const float* __restrict__ b1,
    const float* __restrict__ w2, const float* __restrict__ b2,
    const float* __restrict__ w3, const float* __restrict__ b3,
    float* __restrict__ out)
{
    __shared__ __align__(16) short lds_w[NFRAG * 64 * 8];

    const int lane  = threadIdx.x & 63;
    const int col   = lane & 15;    // A row / B col / pixel-in-tile
    const int lrow  = lane >> 4;    // k-group
    const int wv    = threadIdx.x >> 6;
    const int p     = blockIdx.x * 64 + wv * 16 + col;   // this lane's pixel

    // ---------------- stage weight A-frags into LDS (once per block) -------
    {
        const int cs = lane, c15 = lane & 15, r4 = lane >> 4;
#pragma unroll 1
        for (int fid = threadIdx.x >> 6; fid < NFRAG; fid += 4) {
            const float* src;
            if (fid < 12) {
                const int mt = fid / 3, kb = fid - 3 * mt;
                src = w1 + (16 * mt + c15) * 96 + 32 * kb + 4 * r4;
            } else if (fid < 20) {
                const int f = fid - 12, mt = f >> 1, kb = f & 1;
                src = w2 + (16 * mt + c15) * 64 + 32 * kb + 4 * r4;
            } else {
                const int kb = fid - 20;
                const int row3 = (c15 < 3) ? c15 : 2;   // junk rows unused
                src = w3 + row3 * 64 + 32 * kb + 4 * r4;
            }
            s16x8 frag;
#pragma unroll
            for (int e = 0; e < 8; ++e)
                frag[e] = f2bf(src[(e & 3) + 16 * (e >> 2)]);
            *(s16x8*)&lds_w[(fid * 64 + cs) * 8] = frag;
        }
    }

    // ---------------- biases in regs (f32, per-lane rows) -------------------
    f32x4 b1f[4], b2f[4];
#pragma unroll
    for (int mt = 0; mt < 4; ++mt) {
        b1f[mt] = *(const f32x4*)(b1 + 16 * mt + 4 * lrow);
        b2f[mt] = *(const f32x4*)(b2 + 16 * mt + 4 * lrow);
    }
    const float b3s0 = b3[0], b3s1 = b3[1], b3s2 = b3[2];  // uniform s_loads

    // ---------------- grid-sample -> localB[2] (B-frags, k=local ch) --------
    // localB[kb][e]: level = 2*kb + (e>>2), in-level channel = 4*lrow + (e&3)
    s16x8 localB[2];
    {
        const float* gs[4] = {g0, g1, g2, g3};
        const int    gn[4] = {32, 64, 128, 256};
        const int px = p & 255;
        const int py = p >> 8;
#pragma unroll
        for (int lv = 0; lv < 4; ++lv) {
            const int G = gn[lv];
            const float ix = (float)((2 * px + 1) * (G - 1)) * (1.0f / 512.0f);
            const float iy = (float)((2 * py + 1) * (G - 1)) * (1.0f / 512.0f);
            int ix0 = (int)ix;
            int iy0 = (int)iy;
            if (ix0 > G - 1) ix0 = G - 1;
            if (iy0 > G - 1) iy0 = G - 1;
            const int ix1 = (ix0 + 1 < G - 1) ? (ix0 + 1) : (G - 1);
            const int iy1 = (iy0 + 1 < G - 1) ? (iy0 + 1) : (G - 1);
            const float wx = ix - (float)ix0;
            const float wy = iy - (float)iy0;
            const float w00 = (1.0f - wy) * (1.0f - wx);
            const float w01 = (1.0f - wy) * wx;
            const float w10 = wy * (1.0f - wx);
            const float w11 = wy * wx;
            const int o00 = iy0 * G + ix0;
            const int o01 = iy0 * G + ix1;
            const int o10 = iy1 * G + ix0;
            const int o11 = iy1 * G + ix1;
            const float* g = gs[lv];
            const int GG = G * G;
#pragma unroll
            for (int j = 0; j < 4; ++j) {
                const float* gc = g + (4 * lrow + j) * GG;
                const float v = gc[o00] * w00 + gc[o01] * w01 +
                                gc[o10] * w10 + gc[o11] * w11;
                localB[lv >> 1][(lv & 1) * 4 + j] = f2bf(v);
            }
        }
    }

    __syncthreads();   // LDS frag table ready

    const short* lw = lds_w + lane * 8;      // per-lane base; fid via offset
#define LDSFRAG(fid) (*(const s16x8*)(lw + (fid) * 64 * 8))

    // ---------------- per-batch pipeline ------------------------------------
    float raw[8];
#pragma unroll
    for (int e = 0; e < 8; ++e) {            // pre-issue batch 0 feat
        const int fc = 4 * lrow + (e & 3) + 16 * (e >> 2);
        raw[e] = feat[(fc << 16) + p];
    }

#pragma unroll 1
    for (int b = 0; b < 8; ++b) {
        // layer 1, local part first (doesn't need feat)
        f32x4 c1[4];
#pragma unroll
        for (int mt = 0; mt < 4; ++mt) {
            c1[mt] = b1f[mt];
            c1[mt] = MFMA16(LDSFRAG(mt * 3 + 1), localB[0], c1[mt]);
            c1[mt] = MFMA16(LDSFRAG(mt * 3 + 2), localB[1], c1[mt]);
        }

        // consume this batch's feat, then immediately prefetch next batch
        s16x8 ff;
#pragma unroll
        for (int e = 0; e < 8; ++e) ff[e] = f2bf(raw[e]);
        if (b < 7) {
#pragma unroll
            for (int e = 0; e < 8; ++e) {
                const int fc = 4 * lrow + (e & 3) + 16 * (e >> 2);
                raw[e] = feat[(((b + 1) << 5 | fc) << 16) + p];
            }
        }
#pragma unroll
        for (int mt = 0; mt < 4; ++mt)
            c1[mt] = MFMA16(LDSFRAG(mt * 3), ff, c1[mt]);

        // relu+repack: C-frag is next layer's B-frag per-lane
        s16x8 h1b[2];
        h1b[0] = pack_relu(c1[0], c1[1]);
        h1b[1] = pack_relu(c1[2], c1[3]);

        // layer 2
        f32x4 c2[4];
#pragma unroll
        for (int mt = 0; mt < 4; ++mt) {
            c2[mt] = b2f[mt];
            c2[mt] = MFMA16(LDSFRAG(12 + mt * 2),     h1b[0], c2[mt]);
            c2[mt] = MFMA16(LDSFRAG(12 + mt * 2 + 1), h1b[1], c2[mt]);
        }
        s16x8 h2b[2];
        h2b[0] = pack_relu(c2[0], c2[1]);
        h2b[1] = pack_relu(c2[2], c2[3]);

        // layer 3 (rows 0..2 valid) + store
        f32x4 c3 = {0.f, 0.f, 0.f, 0.f};
        c3 = MFMA16(LDSFRAG(20), h2b[0], c3);
        c3 = MFMA16(LDSFRAG(21), h2b[1], c3);

        if (lrow == 0) {
            out[((b * 3 + 0) << 16) + p] = c3[0] + b3s0;
            out[((b * 3 + 1) << 16) + p] = c3[1] + b3s1;
            out[((b * 3 + 2) << 16) + p] = c3[2] + b3s2;
        }
    }
#undef LDSFRAG
}

extern "C" void kernel_launch(void* const* d_in, const int* in_sizes, int n_in,
                              void* d_out, int out_size, void* d_ws, size_t ws_size,
                              hipStream_t stream) {
    const float* feat = (const float*)d_in[0];
    const float* g0   = (const float*)d_in[1];
    const float* g1   = (const float*)d_in[2];
    const float* g2   = (const float*)d_in[3];
    const float* g3   = (const float*)d_in[4];
    const float* w1   = (const float*)d_in[5];
    const float* b1   = (const float*)d_in[6];
    const float* w2   = (const float*)d_in[7];
    const float* b2   = (const float*)d_in[8];
    const float* w3   = (const float*)d_in[9];
    const float* b3   = (const float*)d_in[10];

    // 65536 px / (16 px/wave * 4 waves) = 1024 blocks; all 8 batches inside.
    grid_inr_mfma<<<1024, 256, 0, stream>>>(
        feat, g0, g1, g2, g3, w1, b1, w2, b2, w3, b3, (float*)d_out);
}

// Round 5
// 30.292 us; speedup vs baseline: 23.1712x; 1.1004x over previous
//
#include <hip/hip_runtime.h>

// Grid_INR2D round 5: bf16-MFMA chain, LDS-read reduction.
//  Round 4 model: LDS pipe dominant (176 ds_read_b128/wave ~14us/CU).
//  Fixes (identical arithmetic order -> absmax unchanged):
//   1. c1base[mt] = b1 + W1[:,32:96]*localB hoisted out of batch loop
//      (batch-invariant local contribution; 8 MFMAs once instead of 64).
//      Per batch: 14 MFMAs (4 w1-feat + 8 w2 + 2 w3).
//   2. w1-feat (4) + w3 (2) frags register-cached after the barrier
//      (+24 VGPR); only the 8 w2 frags stream from LDS per batch.
//      ds_read/batch 22 -> 8; per wave 176 -> ~78.
//   3. __launch_bounds__(256,4): pin VGPR<=128 -> 4 waves/SIMD for the
//      4-blocks/CU grid. Live set ~115 -> no spill expected (watch
//      WRITE_SIZE; 6.1MB = clean, more = spill -> revert caching).
// Fragment identity (validated rounds 3-4):
//   A: row=lane&15, k=4*(lane>>4)+(e&3)+16*(e>>2); B: col=lane&15, same k;
//   C/D: col=lane&15, row=4*(lane>>4)+reg  ==> C-frag of layer n is B-frag
//   of layer n+1 per-lane: B[kb].e = bf16(relu(C[2kb+(e>=4)].reg[e&3])).

typedef float f32x4 __attribute__((ext_vector_type(4)));
typedef short s16x8 __attribute__((ext_vector_type(8)));

#define MFMA16(a, b, c) __builtin_amdgcn_mfma_f32_16x16x32_bf16((a), (b), (c), 0, 0, 0)

__device__ __forceinline__ short f2bf(float f) {  // fp32 -> bf16, RNE
    unsigned u = __builtin_bit_cast(unsigned, f);
    u += 0x7fff + ((u >> 16) & 1);
    return (short)(u >> 16);
}

__device__ __forceinline__ s16x8 pack_relu(const f32x4 lo, const f32x4 hi) {
    s16x8 r;
#pragma unroll
    for (int e = 0; e < 4; ++e) {
        r[e]     = f2bf(fmaxf(lo[e], 0.0f));
        r[e + 4] = f2bf(fmaxf(hi[e], 0.0f));
    }
    return r;
}

// LDS frag table: fid 0..11 = w1[mt*3+kb], 12..19 = w2[mt*2+kb], 20..21 = w3[kb]
#define NFRAG 22

__global__ __launch_bounds__(256, 4) void grid_inr_mfma(
    const float* __restrict__ feat,
    const float* __restrict__ g0, const float* __restrict__ g1,
    const float* __restrict__ g2, const float* __restrict__ g3,
    const float* __restrict__ w1, const float* __restrict__ b1,
    const float* __restrict__ w2, const float* __restrict__ b2,
    const float* __restrict__ w3, const float* __restrict__ b3,
    float* __restrict__ out)
{
    __shared__ __align__(16) short lds_w[NFRAG * 64 * 8];

    const int lane  = threadIdx.x & 63;
    const int col   = lane & 15;    // A row / B col / pixel-in-tile
    const int lrow  = lane >> 4;    // k-group
    const int wv    = threadIdx.x >> 6;
    const int p     = blockIdx.x * 64 + wv * 16 + col;   // this lane's pixel

    // ---------------- stage weight A-frags into LDS (once per block) -------
    {
        const int cs = lane, c15 = lane & 15, r4 = lane >> 4;
#pragma unroll 1
        for (int fid = threadIdx.x >> 6; fid < NFRAG; fid += 4) {
            const float* src;
            if (fid < 12) {
                const int mt = fid / 3, kb = fid - 3 * mt;
                src = w1 + (16 * mt + c15) * 96 + 32 * kb + 4 * r4;
            } else if (fid < 20) {
                const int f = fid - 12, mt = f >> 1, kb = f & 1;
                src = w2 + (16 * mt + c15) * 64 + 32 * kb + 4 * r4;
            } else {
                const int kb = fid - 20;
                const int row3 = (c15 < 3) ? c15 : 2;   // junk rows unused
                src = w3 + row3 * 64 + 32 * kb + 4 * r4;
            }
            s16x8 frag;
#pragma unroll
            for (int e = 0; e < 8; ++e)
                frag[e] = f2bf(src[(e & 3) + 16 * (e >> 2)]);
            *(s16x8*)&lds_w[(fid * 64 + cs) * 8] = frag;
        }
    }

    // ---------------- biases in regs (f32, per-lane rows) -------------------
    f32x4 b1f[4], b2f[4];
#pragma unroll
    for (int mt = 0; mt < 4; ++mt) {
        b1f[mt] = *(const f32x4*)(b1 + 16 * mt + 4 * lrow);
        b2f[mt] = *(const f32x4*)(b2 + 16 * mt + 4 * lrow);
    }
    const float b3s0 = b3[0], b3s1 = b3[1], b3s2 = b3[2];  // uniform s_loads

    // ---------------- grid-sample -> localB[2] (B-frags, k=local ch) --------
    s16x8 localB[2];
    {
        const float* gs[4] = {g0, g1, g2, g3};
        const int    gn[4] = {32, 64, 128, 256};
        const int px = p & 255;
        const int py = p >> 8;
#pragma unroll
        for (int lv = 0; lv < 4; ++lv) {
            const int G = gn[lv];
            const float ix = (float)((2 * px + 1) * (G - 1)) * (1.0f / 512.0f);
            const float iy = (float)((2 * py + 1) * (G - 1)) * (1.0f / 512.0f);
            int ix0 = (int)ix;
            int iy0 = (int)iy;
            if (ix0 > G - 1) ix0 = G - 1;
            if (iy0 > G - 1) iy0 = G - 1;
            const int ix1 = (ix0 + 1 < G - 1) ? (ix0 + 1) : (G - 1);
            const int iy1 = (iy0 + 1 < G - 1) ? (iy0 + 1) : (G - 1);
            const float wx = ix - (float)ix0;
            const float wy = iy - (float)iy0;
            const float w00 = (1.0f - wy) * (1.0f - wx);
            const float w01 = (1.0f - wy) * wx;
            const float w10 = wy * (1.0f - wx);
            const float w11 = wy * wx;
            const int o00 = iy0 * G + ix0;
            const int o01 = iy0 * G + ix1;
            const int o10 = iy1 * G + ix0;
            const int o11 = iy1 * G + ix1;
            const float* g = gs[lv];
            const int GG = G * G;
#pragma unroll
            for (int j = 0; j < 4; ++j) {
                const float* gc = g + (4 * lrow + j) * GG;
                const float v = gc[o00] * w00 + gc[o01] * w01 +
                                gc[o10] * w10 + gc[o11] * w11;
                localB[lv >> 1][(lv & 1) * 4 + j] = f2bf(v);
            }
        }
    }

    __syncthreads();   // LDS frag table ready

    const short* lw = lds_w + lane * 8;      // per-lane base; fid via offset
#define LDSFRAG(fid) (*(const s16x8*)(lw + (fid) * 64 * 8))

    // ---- register-cache small frag groups; hoist batch-invariant layer-1 ---
    s16x8 w1ff[4], w3f[2];
#pragma unroll
    for (int mt = 0; mt < 4; ++mt) w1ff[mt] = LDSFRAG(mt * 3);
    w3f[0] = LDSFRAG(20);
    w3f[1] = LDSFRAG(21);

    // c1base[mt] = b1 + W1[:,32:96] . local   (batch-invariant, once)
    f32x4 c1base[4];
#pragma unroll
    for (int mt = 0; mt < 4; ++mt) {
        c1base[mt] = b1f[mt];
        c1base[mt] = MFMA16(LDSFRAG(mt * 3 + 1), localB[0], c1base[mt]);
        c1base[mt] = MFMA16(LDSFRAG(mt * 3 + 2), localB[1], c1base[mt]);
    }

    // ---------------- per-batch pipeline ------------------------------------
    float raw[8];
#pragma unroll
    for (int e = 0; e < 8; ++e) {            // pre-issue batch 0 feat
        const int fc = 4 * lrow + (e & 3) + 16 * (e >> 2);
        raw[e] = feat[(fc << 16) + p];
    }

#pragma unroll 1
    for (int b = 0; b < 8; ++b) {
        // consume this batch's feat, then immediately prefetch next batch
        s16x8 ff;
#pragma unroll
        for (int e = 0; e < 8; ++e) ff[e] = f2bf(raw[e]);
        if (b < 7) {
#pragma unroll
            for (int e = 0; e < 8; ++e) {
                const int fc = 4 * lrow + (e & 3) + 16 * (e >> 2);
                raw[e] = feat[(((b + 1) << 5 | fc) << 16) + p];
            }
        }

        // layer 1: single MFMA per mtile, seeded from batch-invariant base
        f32x4 c1[4];
#pragma unroll
        for (int mt = 0; mt < 4; ++mt)
            c1[mt] = MFMA16(w1ff[mt], ff, c1base[mt]);

        // relu+repack: C-frag is next layer's B-frag per-lane
        s16x8 h1b[2];
        h1b[0] = pack_relu(c1[0], c1[1]);
        h1b[1] = pack_relu(c1[2], c1[3]);

        // layer 2 (8 frags streamed from LDS)
        f32x4 c2[4];
#pragma unroll
        for (int mt = 0; mt < 4; ++mt) {
            c2[mt] = b2f[mt];
            c2[mt] = MFMA16(LDSFRAG(12 + mt * 2),     h1b[0], c2[mt]);
            c2[mt] = MFMA16(LDSFRAG(12 + mt * 2 + 1), h1b[1], c2[mt]);
        }
        s16x8 h2b[2];
        h2b[0] = pack_relu(c2[0], c2[1]);
        h2b[1] = pack_relu(c2[2], c2[3]);

        // layer 3 (rows 0..2 valid) + store
        f32x4 c3 = {0.f, 0.f, 0.f, 0.f};
        c3 = MFMA16(w3f[0], h2b[0], c3);
        c3 = MFMA16(w3f[1], h2b[1], c3);

        if (lrow == 0) {
            out[((b * 3 + 0) << 16) + p] = c3[0] + b3s0;
            out[((b * 3 + 1) << 16) + p] = c3[1] + b3s1;
            out[((b * 3 + 2) << 16) + p] = c3[2] + b3s2;
        }
    }
#undef LDSFRAG
}

extern "C" void kernel_launch(void* const* d_in, const int* in_sizes, int n_in,
                              void* d_out, int out_size, void* d_ws, size_t ws_size,
                              hipStream_t stream) {
    const float* feat = (const float*)d_in[0];
    const float* g0   = (const float*)d_in[1];
    const float* g1   = (const float*)d_in[2];
    const float* g2   = (const float*)d_in[3];
    const float* g3   = (const float*)d_in[4];
    const float* w1   = (const float*)d_in[5];
    const float* b1   = (const float*)d_in[6];
    const float* w2   = (const float*)d_in[7];
    const float* b2   = (const float*)d_in[8];
    const float* w3   = (const float*)d_in[9];
    const float* b3   = (const float*)d_in[10];

    // 65536 px / (16 px/wave * 4 waves) = 1024 blocks; all 8 batches inside.
    grid_inr_mfma<<<1024, 256, 0, stream>>>(
        feat, g0, g1, g2, g3, w1, b1, w2, b2, w3, b3, (float*)d_out);
}

// Round 6
// 28.809 us; speedup vs baseline: 24.3643x; 1.0515x over previous
//
#include <hip/hip_runtime.h>
#include <hip/hip_bf16.h>

// Grid_INR2D round 6: native cvt_pk conversions + 2-deep feat prefetch.
//  Round 5 model: bit-twiddle f2bf = ~6.5 VALU/value -> ~7us/SIMD of pack
//  cost; 1-batch-ahead prefetch (~500cy) < L3 latency -> all-wave stalls.
//  Fixes:
//   1. scalar __float2bfloat16 casts (compiler fuses pairs into
//      v_cvt_pk_bf16_f32 — m240: scalar cast beats hand-written RNE/asm).
//   2. feat prefetch depth 2: rawP/rawQ ping-pong (named arrays, static
//      indexing), loads issued ~2 batch-bodies before use.
//  Structure from round 5 kept: weights in LDS (22 frags), w1-feat/w3
//  reg-cached, batch-invariant c1base hoist, 16px/wave, 1024 blocks.
// Fragment identity (validated rounds 3-5):
//   A: row=lane&15, k=4*(lane>>4)+(e&3)+16*(e>>2); B: col=lane&15, same k;
//   C/D: col=lane&15, row=4*(lane>>4)+reg  ==> C-frag of layer n is B-frag
//   of layer n+1 per-lane: B[kb].e = bf16(relu(C[2kb+(e>=4)].reg[e&3])).

typedef float f32x4 __attribute__((ext_vector_type(4)));
typedef short s16x8 __attribute__((ext_vector_type(8)));

#define MFMA16(a, b, c) __builtin_amdgcn_mfma_f32_16x16x32_bf16((a), (b), (c), 0, 0, 0)

__device__ __forceinline__ short bfbits(float f) {   // RNE via HW cvt
    return __builtin_bit_cast(short, __float2bfloat16(f));
}

__device__ __forceinline__ s16x8 pack_relu(const f32x4 lo, const f32x4 hi) {
    s16x8 r;
#pragma unroll
    for (int e = 0; e < 4; ++e) {
        r[e]     = bfbits(fmaxf(lo[e], 0.0f));
        r[e + 4] = bfbits(fmaxf(hi[e], 0.0f));
    }
    return r;
}

// LDS frag table: fid 0..11 = w1[mt*3+kb], 12..19 = w2[mt*2+kb], 20..21 = w3[kb]
#define NFRAG 22

__global__ __launch_bounds__(256, 4) void grid_inr_mfma(
    const float* __restrict__ feat,
    const float* __restrict__ g0, const float* __restrict__ g1,
    const float* __restrict__ g2, const float* __restrict__ g3,
    const float* __restrict__ w1, const float* __restrict__ b1,
    const float* __restrict__ w2, const float* __restrict__ b2,
    const float* __restrict__ w3, const float* __restrict__ b3,
    float* __restrict__ out)
{
    __shared__ __align__(16) short lds_w[NFRAG * 64 * 8];

    const int lane  = threadIdx.x & 63;
    const int col   = lane & 15;    // A row / B col / pixel-in-tile
    const int lrow  = lane >> 4;    // k-group
    const int wv    = threadIdx.x >> 6;
    const int p     = blockIdx.x * 64 + wv * 16 + col;   // this lane's pixel

    // ---------------- stage weight A-frags into LDS (once per block) -------
    {
        const int cs = lane, c15 = lane & 15, r4 = lane >> 4;
#pragma unroll 1
        for (int fid = threadIdx.x >> 6; fid < NFRAG; fid += 4) {
            const float* src;
            if (fid < 12) {
                const int mt = fid / 3, kb = fid - 3 * mt;
                src = w1 + (16 * mt + c15) * 96 + 32 * kb + 4 * r4;
            } else if (fid < 20) {
                const int f = fid - 12, mt = f >> 1, kb = f & 1;
                src = w2 + (16 * mt + c15) * 64 + 32 * kb + 4 * r4;
            } else {
                const int kb = fid - 20;
                const int row3 = (c15 < 3) ? c15 : 2;   // junk rows unused
                src = w3 + row3 * 64 + 32 * kb + 4 * r4;
            }
            s16x8 frag;
#pragma unroll
            for (int e = 0; e < 8; ++e)
                frag[e] = bfbits(src[(e & 3) + 16 * (e >> 2)]);
            *(s16x8*)&lds_w[(fid * 64 + cs) * 8] = frag;
        }
    }

    // ---------------- biases in regs (f32, per-lane rows) -------------------
    f32x4 b1f[4], b2f[4];
#pragma unroll
    for (int mt = 0; mt < 4; ++mt) {
        b1f[mt] = *(const f32x4*)(b1 + 16 * mt + 4 * lrow);
        b2f[mt] = *(const f32x4*)(b2 + 16 * mt + 4 * lrow);
    }
    const float b3s0 = b3[0], b3s1 = b3[1], b3s2 = b3[2];  // uniform s_loads

    // ---------------- grid-sample -> localB[2] (B-frags, k=local ch) --------
    s16x8 localB[2];
    {
        const float* gs[4] = {g0, g1, g2, g3};
        const int    gn[4] = {32, 64, 128, 256};
        const int px = p & 255;
        const int py = p >> 8;
#pragma unroll
        for (int lv = 0; lv < 4; ++lv) {
            const int G = gn[lv];
            const float ix = (float)((2 * px + 1) * (G - 1)) * (1.0f / 512.0f);
            const float iy = (float)((2 * py + 1) * (G - 1)) * (1.0f / 512.0f);
            int ix0 = (int)ix;
            int iy0 = (int)iy;
            if (ix0 > G - 1) ix0 = G - 1;
            if (iy0 > G - 1) iy0 = G - 1;
            const int ix1 = (ix0 + 1 < G - 1) ? (ix0 + 1) : (G - 1);
            const int iy1 = (iy0 + 1 < G - 1) ? (iy0 + 1) : (G - 1);
            const float wx = ix - (float)ix0;
            const float wy = iy - (float)iy0;
            const float w00 = (1.0f - wy) * (1.0f - wx);
            const float w01 = (1.0f - wy) * wx;
            const float w10 = wy * (1.0f - wx);
            const float w11 = wy * wx;
            const int o00 = iy0 * G + ix0;
            const int o01 = iy0 * G + ix1;
            const int o10 = iy1 * G + ix0;
            const int o11 = iy1 * G + ix1;
            const float* g = gs[lv];
            const int GG = G * G;
#pragma unroll
            for (int j = 0; j < 4; ++j) {
                const float* gc = g + (4 * lrow + j) * GG;
                const float v = gc[o00] * w00 + gc[o01] * w01 +
                                gc[o10] * w10 + gc[o11] * w11;
                localB[lv >> 1][(lv & 1) * 4 + j] = bfbits(v);
            }
        }
    }

    __syncthreads();   // LDS frag table ready

    const short* lw = lds_w + lane * 8;      // per-lane base; fid via offset
#define LDSFRAG(fid) (*(const s16x8*)(lw + (fid) * 64 * 8))

    // ---- register-cache small frag groups; hoist batch-invariant layer-1 ---
    s16x8 w1ff[4], w3f[2];
#pragma unroll
    for (int mt = 0; mt < 4; ++mt) w1ff[mt] = LDSFRAG(mt * 3);
    w3f[0] = LDSFRAG(20);
    w3f[1] = LDSFRAG(21);

    // c1base[mt] = b1 + W1[:,32:96] . local   (batch-invariant, once)
    f32x4 c1base[4];
#pragma unroll
    for (int mt = 0; mt < 4; ++mt) {
        c1base[mt] = b1f[mt];
        c1base[mt] = MFMA16(LDSFRAG(mt * 3 + 1), localB[0], c1base[mt]);
        c1base[mt] = MFMA16(LDSFRAG(mt * 3 + 2), localB[1], c1base[mt]);
    }

    // ---- per-batch MLP body (b only feeds store addressing) ----------------
    auto process = [&](int b, const s16x8 ff) {
        f32x4 c1[4];
#pragma unroll
        for (int mt = 0; mt < 4; ++mt)
            c1[mt] = MFMA16(w1ff[mt], ff, c1base[mt]);

        s16x8 h1b0 = pack_relu(c1[0], c1[1]);
        s16x8 h1b1 = pack_relu(c1[2], c1[3]);

        f32x4 c2[4];
#pragma unroll
        for (int mt = 0; mt < 4; ++mt) {
            c2[mt] = b2f[mt];
            c2[mt] = MFMA16(LDSFRAG(12 + mt * 2),     h1b0, c2[mt]);
            c2[mt] = MFMA16(LDSFRAG(12 + mt * 2 + 1), h1b1, c2[mt]);
        }
        s16x8 h2b0 = pack_relu(c2[0], c2[1]);
        s16x8 h2b1 = pack_relu(c2[2], c2[3]);

        f32x4 c3 = {0.f, 0.f, 0.f, 0.f};
        c3 = MFMA16(w3f[0], h2b0, c3);
        c3 = MFMA16(w3f[1], h2b1, c3);

        if (lrow == 0) {
            out[((b * 3 + 0) << 16) + p] = c3[0] + b3s0;
            out[((b * 3 + 1) << 16) + p] = c3[1] + b3s1;
            out[((b * 3 + 2) << 16) + p] = c3[2] + b3s2;
        }
    };

    // ---- batch loop: 2-deep feat prefetch via named ping-pong buffers ------
    float rawP[8], rawQ[8];
#pragma unroll
    for (int e = 0; e < 8; ++e) {
        const int fc = 4 * lrow + (e & 3) + 16 * (e >> 2);
        rawP[e] = feat[(fc << 16) + p];          // batch 0
        rawQ[e] = feat[((32 + fc) << 16) + p];   // batch 1
    }

#pragma unroll 1
    for (int bp = 0; bp < 4; ++bp) {
        // batch A = 2*bp (from rawP); refill rawP with batch 2*bp+2
        s16x8 ff;
#pragma unroll
        for (int e = 0; e < 8; ++e) ff[e] = bfbits(rawP[e]);
        if (bp < 3) {
#pragma unroll
            for (int e = 0; e < 8; ++e) {
                const int fc = 4 * lrow + (e & 3) + 16 * (e >> 2);
                rawP[e] = feat[((((2 * bp + 2) << 5) | fc) << 16) + p];
            }
        }
        process(2 * bp, ff);

        // batch B = 2*bp+1 (from rawQ); refill rawQ with batch 2*bp+3
#pragma unroll
        for (int e = 0; e < 8; ++e) ff[e] = bfbits(rawQ[e]);
        if (bp < 3) {
#pragma unroll
            for (int e = 0; e < 8; ++e) {
                const int fc = 4 * lrow + (e & 3) + 16 * (e >> 2);
                rawQ[e] = feat[((((2 * bp + 3) << 5) | fc) << 16) + p];
            }
        }
        process(2 * bp + 1, ff);
    }
#undef LDSFRAG
}

extern "C" void kernel_launch(void* const* d_in, const int* in_sizes, int n_in,
                              void* d_out, int out_size, void* d_ws, size_t ws_size,
                              hipStream_t stream) {
    const float* feat = (const float*)d_in[0];
    const float* g0   = (const float*)d_in[1];
    const float* g1   = (const float*)d_in[2];
    const float* g2   = (const float*)d_in[3];
    const float* g3   = (const float*)d_in[4];
    const float* w1   = (const float*)d_in[5];
    const float* b1   = (const float*)d_in[6];
    const float* w2   = (const float*)d_in[7];
    const float* b2   = (const float*)d_in[8];
    const float* w3   = (const float*)d_in[9];
    const float* b3   = (const float*)d_in[10];

    // 65536 px / (16 px/wave * 4 waves) = 1024 blocks; all 8 batches inside.
    grid_inr_mfma<<<1024, 256, 0, stream>>>(
        feat, g0, g1, g2, g3, w1, b1, w2, b2, w3, b3, (float*)d_out);
}